// Round 6
// baseline (1850.126 us; speedup 1.0000x reference)
//
#include <hip/hip_runtime.h>
#include <hip/hip_bf16.h>
#include <stdint.h>

#define B_ 4
#define N_ 8192
#define D_ 128
#define E_ 262144

typedef __bf16 bf16x8 __attribute__((ext_vector_type(8)));
typedef unsigned short u16x8 __attribute__((ext_vector_type(8)));
typedef float f32x4 __attribute__((ext_vector_type(4)));

constexpr int BUCKET_CAP = 128;   // Poisson(32)/src; P(>=128) ~ 1e-40
constexpr int TILES = 2;          // 64-edge tiles per edge_mlp block
constexpr int GRID_MLP = E_ / (64 * TILES);   // 2048 blocks = 8/CU, load-balanced

// ws layout (bytes):
constexpr size_t OFF_HB     = 0;          // bf16 h [B][N][D]         8,388,608
constexpr size_t OFF_W1T    = 8388608;    // bf16 W1^T [128][256]        65,536
constexpr size_t OFF_SCORES = 8454144;    // float4 scores [E]        4,194,304
constexpr size_t OFF_CNT    = 12648448;   // int cnt [N]                 32,768
constexpr size_t OFF_BASE   = 12681216;   // int base [N]                32,768
constexpr size_t OFF_BUCKET = 12713984;   // int bucket [N][128]      4,194,304
constexpr size_t OFF_ORDER  = 16908288;   // int order [E]            1,048,576

__device__ __forceinline__ unsigned short f2bf(float f) {
  union { float f; unsigned u; } v; v.f = f;
  unsigned r = v.u + 0x7fffu + ((v.u >> 16) & 1u);  // RNE
  return (unsigned short)(r >> 16);
}

__global__ void cast_h_k(const float* __restrict__ h, unsigned short* __restrict__ o) {
  int i = blockIdx.x * blockDim.x + threadIdx.x;   // 1,048,576 threads x 4 elems
  float4 v = reinterpret_cast<const float4*>(h)[i];
  ushort4 r;
  r.x = f2bf(v.x); r.y = f2bf(v.y); r.z = f2bf(v.z); r.w = f2bf(v.w);
  reinterpret_cast<ushort4*>(o)[i] = r;
}

__global__ void tw1_k(const float* __restrict__ W1, unsigned short* __restrict__ o) {
  int i = blockIdx.x * blockDim.x + threadIdx.x;   // 32768: i = d*256 + k
  int d = i >> 8, k = i & 255;
  o[i] = f2bf(W1[k * 128 + d]);
}

// append every edge to its src bucket (order within bucket irrelevant)
__global__ void place_k(const int* __restrict__ ei,
                        int* __restrict__ cnt, int* __restrict__ bucket) {
  int e = blockIdx.x * blockDim.x + threadIdx.x;
  int s = ei[e];
  int pos = atomicAdd(&cnt[s], 1);
  if (pos < BUCKET_CAP) bucket[s * BUCKET_CAP + pos] = e;
}

// exclusive prefix sum of clamped counts -> base[]
__global__ void prefix_k(const int* __restrict__ cnt, int* __restrict__ base) {
  __shared__ int sc[256];
  const int t = threadIdx.x;
  int c[32];
  int local = 0;
  #pragma unroll
  for (int j = 0; j < 32; ++j) {
    int v = cnt[t * 32 + j];
    v = v < BUCKET_CAP ? v : BUCKET_CAP;
    c[j] = v; local += v;
  }
  sc[t] = local;
  __syncthreads();
  #pragma unroll
  for (int off = 1; off < 256; off <<= 1) {
    int v = (t >= off) ? sc[t - off] : 0;
    __syncthreads();
    sc[t] += v;
    __syncthreads();
  }
  int run = sc[t] - local;                  // exclusive
  #pragma unroll
  for (int j = 0; j < 32; ++j) { base[t * 32 + j] = run; run += c[j]; }
}

// flatten buckets -> src-grouped order[]
__global__ void order_build_k(const int* __restrict__ cnt, const int* __restrict__ base,
                              const int* __restrict__ bucket, int* __restrict__ order) {
  int s = blockIdx.x * blockDim.x + threadIdx.x;   // 8192 threads
  int n = cnt[s]; n = n < BUCKET_CAP ? n : BUCKET_CAP;
  int b0 = base[s];
  for (int j = 0; j < n; ++j) order[b0 + j] = bucket[s * BUCKET_CAP + j];
}

// 512 threads, 8 waves; TILES tiles of 64 edges; M=256 rows (row=e_local*4+b),
// K=256, N=128. Wave w owns rows [w*32, w*32+32). W1^T staged once per block.
__global__ __launch_bounds__(512, 4) void edge_mlp_k(
    const int* __restrict__ ei,
    const int* __restrict__ order,
    const unsigned short* __restrict__ hb,    // bf16 bits [B][N][D]
    const unsigned short* __restrict__ w1t,   // bf16 bits [128][256]
    const float* __restrict__ b1,
    const float* __restrict__ w2,
    const float* __restrict__ b2,
    f32x4* __restrict__ scores) {             // [E] = {b0,b1,b2,b3}
  __shared__ char lds[65536];                 // W1^T, XOR-swizzled rows of 512 B
  const int tid  = threadIdx.x;
  const int lane = tid & 63;
  const int wid  = tid >> 6;                  // 0..7
  const int l15  = lane & 15;
  const int lg   = lane >> 4;

  {
    const uint4* g = reinterpret_cast<const uint4*>(w1t);
    #pragma unroll
    for (int it = 0; it < 8; ++it) {
      int i = it * 512 + tid;                 // uint4 index, 4096 total
      uint4 v = g[i];
      int byte = i * 16;
      int dd = byte >> 9;
      int within = byte & 511;
      *reinterpret_cast<uint4*>(&lds[dd * 512 + (within ^ ((dd & 7) << 4))]) = v;
    }
  }
  __syncthreads();

  // preload epilogue constants once
  float b1v[8], w2v[8];
  #pragma unroll
  for (int n = 0; n < 8; ++n) {
    int col = n * 16 + l15;
    b1v[n] = b1[col];
    w2v[n] = w2[col];
  }
  const float b2v = b2[0];
  const int kg = 8 * lg;

  #pragma unroll 1
  for (int tile = 0; tile < TILES; ++tile) {
    const int t0 = (blockIdx.x * TILES + tile) * 64;

    unsigned offS[2], offD[2];
    #pragma unroll
    for (int m = 0; m < 2; ++m) {
      int row = wid * 32 + m * 16 + l15;
      int e = order[t0 + (row >> 2)];
      int b = row & 3;
      offS[m] = ((unsigned)b * N_ + (unsigned)ei[e]) * D_;
      offD[m] = ((unsigned)b * N_ + (unsigned)ei[E_ + e]) * D_;
    }

    f32x4 acc[2][8];
    #pragma unroll
    for (int m = 0; m < 2; ++m)
      #pragma unroll
      for (int n = 0; n < 8; ++n)
        acc[m][n] = (f32x4){0.f, 0.f, 0.f, 0.f};

    #pragma unroll
    for (int ks = 0; ks < 8; ++ks) {
      bf16x8 a[2];
      const int kin = (ks & 3) * 32 + kg;
      #pragma unroll
      for (int m = 0; m < 2; ++m) {
        unsigned off = (ks < 4 ? offS[m] : offD[m]) + (unsigned)kin;
        u16x8 u = *reinterpret_cast<const u16x8*>(hb + off);
        a[m] = __builtin_bit_cast(bf16x8, u);
      }
      const int kb = ks * 64 + 16 * lg;
      #pragma unroll
      for (int n = 0; n < 8; ++n) {
        int dd = n * 16 + l15;
        uint4 v = *reinterpret_cast<const uint4*>(&lds[dd * 512 + (kb ^ ((dd & 7) << 4))]);
        bf16x8 bfr = __builtin_bit_cast(bf16x8, v);
        acc[0][n] = __builtin_amdgcn_mfma_f32_16x16x32_bf16(a[0], bfr, acc[0][n], 0, 0, 0);
        acc[1][n] = __builtin_amdgcn_mfma_f32_16x16x32_bf16(a[1], bfr, acc[1][n], 0, 0, 0);
      }
    }

    float sc[2][4];
    #pragma unroll
    for (int m = 0; m < 2; ++m)
      #pragma unroll
      for (int i = 0; i < 4; ++i) sc[m][i] = 0.f;
    #pragma unroll
    for (int n = 0; n < 8; ++n)
      #pragma unroll
      for (int m = 0; m < 2; ++m)
        #pragma unroll
        for (int i = 0; i < 4; ++i) {
          float v = acc[m][n][i] + b1v[n];
          float sv = v / (1.f + __expf(-v));    // SiLU
          sc[m][i] += sv * w2v[n];
        }
    #pragma unroll
    for (int m = 0; m < 2; ++m)
      #pragma unroll
      for (int i = 0; i < 4; ++i) {
        float v = sc[m][i];
        v += __shfl_xor(v, 1, 64);
        v += __shfl_xor(v, 2, 64);
        v += __shfl_xor(v, 4, 64);
        v += __shfl_xor(v, 8, 64);
        sc[m][i] = v;
      }
    if (l15 == 0) {
      // lane's 4 acc regs = rows base..base+3 = the 4 batches of one edge
      #pragma unroll
      for (int m = 0; m < 2; ++m) {
        int base_row = wid * 32 + m * 16 + 4 * lg;
        int e_w = order[t0 + (base_row >> 2)];
        scores[e_w] = (f32x4){sc[m][0] + b2v, sc[m][1] + b2v, sc[m][2] + b2v, sc[m][3] + b2v};
      }
    }
  }
}

// One block per src row. Dedupe (max-e wins) in LDS, mark idx8[dst]=t+1,
// then stream all 4 batches' rows with each float4 written exactly once.
__global__ __launch_bounds__(256, 8) void out_writer_k(
    const int* __restrict__ ei,
    const int* __restrict__ cnt,
    const int* __restrict__ bucket,
    const f32x4* __restrict__ scores,
    float* __restrict__ out) {
  __shared__ int dst_l[BUCKET_CAP];
  __shared__ int e_l[BUCKET_CAP];
  __shared__ float sc4[BUCKET_CAP][4];
  __shared__ unsigned int idx32[2048];        // u8 mark per dst elem (8192)
  const int t = threadIdx.x;
  const int src = blockIdx.x;
  int n = cnt[src];
  n = n < BUCKET_CAP ? n : BUCKET_CAP;
  if (t < n) {
    int e = bucket[src * BUCKET_CAP + t];
    e_l[t] = e;
    dst_l[t] = ei[E_ + e];
    f32x4 s = scores[e];
    sc4[t][0] = s[0]; sc4[t][1] = s[1]; sc4[t][2] = s[2]; sc4[t][3] = s[3];
  }
  #pragma unroll
  for (int k = 0; k < 8; ++k) idx32[t + 256 * k] = 0u;
  __syncthreads();
  if (t < n) {
    int dst = dst_l[t], e = e_l[t];
    bool win = true;
    for (int j = 0; j < n; ++j)
      win = win && !(dst_l[j] == dst && e_l[j] > e);
    if (win) reinterpret_cast<unsigned char*>(idx32)[dst] = (unsigned char)(t + 1);
  }
  __syncthreads();

  const size_t rowbase = (size_t)src * N_;
  #pragma unroll
  for (int b = 0; b < 4; ++b) {
    f32x4* po = reinterpret_cast<f32x4*>(out + (size_t)b * ((size_t)N_ * N_) + rowbase);
    #pragma unroll
    for (int k = 0; k < 8; ++k) {
      int c = t + 256 * k;                    // float4 chunk: dsts [4c, 4c+4)
      unsigned m4 = idx32[c];
      f32x4 v = (f32x4){0.f, 0.f, 0.f, 0.f};
      if (m4) {
        #pragma unroll
        for (int i = 0; i < 4; ++i) {
          unsigned mj = (m4 >> (8 * i)) & 255u;
          if (mj) v[i] = sc4[mj - 1][b];
        }
      }
      po[c] = v;                              // regular store (L2 write-combine)
    }
  }
}

extern "C" void kernel_launch(void* const* d_in, const int* in_sizes, int n_in,
                              void* d_out, int out_size, void* d_ws, size_t ws_size,
                              hipStream_t stream) {
  const float* h  = (const float*)d_in[0];
  const int*   ei = (const int*)d_in[1];     // harness stores integer inputs as int32
  const float* W1 = (const float*)d_in[2];
  const float* b1 = (const float*)d_in[3];
  const float* W2 = (const float*)d_in[4];
  const float* b2 = (const float*)d_in[5];
  float* out = (float*)d_out;
  char*  ws  = (char*)d_ws;

  unsigned short* hb     = (unsigned short*)(ws + OFF_HB);
  unsigned short* w1t    = (unsigned short*)(ws + OFF_W1T);
  f32x4*          scores = (f32x4*)(ws + OFF_SCORES);
  int*            cnt    = (int*)(ws + OFF_CNT);
  int*            base   = (int*)(ws + OFF_BASE);
  int*            bucket = (int*)(ws + OFF_BUCKET);
  int*            order  = (int*)(ws + OFF_ORDER);

  (void)hipMemsetAsync(cnt, 0, (size_t)N_ * 4, stream);
  (void)hipMemsetAsync(order, 0, (size_t)E_ * 4, stream);  // safe pad if overflow

  cast_h_k<<<4096, 256, 0, stream>>>(h, hb);
  tw1_k<<<128, 256, 0, stream>>>(W1, w1t);
  place_k<<<E_ / 256, 256, 0, stream>>>(ei, cnt, bucket);
  prefix_k<<<1, 256, 0, stream>>>(cnt, base);
  order_build_k<<<32, 256, 0, stream>>>(cnt, base, bucket, order);
  edge_mlp_k<<<GRID_MLP, 512, 0, stream>>>(ei, order, hb, w1t, b1, W2, b2, scores);
  out_writer_k<<<N_, 256, 0, stream>>>(ei, cnt, bucket, scores, out);
}

// Round 7
// 1225.745 us; speedup vs baseline: 1.5094x; 1.5094x over previous
//
#include <hip/hip_runtime.h>
#include <hip/hip_bf16.h>
#include <stdint.h>

#define B_ 4
#define N_ 8192
#define D_ 128
#define E_ 262144

typedef __bf16 bf16x8 __attribute__((ext_vector_type(8)));
typedef unsigned short u16x8 __attribute__((ext_vector_type(8)));
typedef float f32x4 __attribute__((ext_vector_type(4)));

constexpr int BUCKET_CAP = 128;   // Poisson(32)/src; P(>=128) ~ 1e-40

// ws layout (bytes):
constexpr size_t OFF_HB     = 0;          // bf16 h [B*N][128]        8,388,608
constexpr size_t OFF_BT     = 8388608;    // bf16 BmatT [256][128]       65,536
constexpr size_t OFF_P      = 8454144;    // bf16 P [B][N][128]       8,388,608
constexpr size_t OFF_Q      = 16842752;   // bf16 Q [B][N][128]       8,388,608
constexpr size_t OFF_SCORES = 25231360;   // float scores [E][4]      4,194,304
constexpr size_t OFF_CNT    = 29425664;   // int cnt [N]                 32,768
constexpr size_t OFF_BASE   = 29458432;   // int base [N]                32,768
constexpr size_t OFF_BUCKET = 29491200;   // int bucket [N][128]      4,194,304
constexpr size_t OFF_ORDER  = 33685504;   // int order [E]            1,048,576

__device__ __forceinline__ unsigned short f2bf(float f) {
  union { float f; unsigned u; } v; v.f = f;
  unsigned r = v.u + 0x7fffu + ((v.u >> 16) & 1u);  // RNE
  return (unsigned short)(r >> 16);
}
__device__ __forceinline__ float bf2f(unsigned short u) {
  return __uint_as_float((unsigned)u << 16);
}

__global__ void cast_h_k(const float* __restrict__ h, unsigned short* __restrict__ o) {
  int i = blockIdx.x * blockDim.x + threadIdx.x;   // 1,048,576 threads x 4 elems
  float4 v = reinterpret_cast<const float4*>(h)[i];
  ushort4 r;
  r.x = f2bf(v.x); r.y = f2bf(v.y); r.z = f2bf(v.z); r.w = f2bf(v.w);
  reinterpret_cast<ushort4*>(o)[i] = r;
}

// BmatT[d'][k], d'<128: W1[k][d'] (top half); d'>=128: W1[128+k][d'-128] (bottom)
__global__ void bmat_k(const float* __restrict__ W1, unsigned short* __restrict__ o) {
  int i = blockIdx.x * blockDim.x + threadIdx.x;   // 32768
  int dp = i >> 7, k = i & 127;
  int kk = (dp < 128) ? k : (128 + k);
  o[i] = f2bf(W1[kk * 128 + (dp & 127)]);
}

// append every edge to its src bucket (order within bucket irrelevant)
__global__ void place_k(const int* __restrict__ ei,
                        int* __restrict__ cnt, int* __restrict__ bucket) {
  int e = blockIdx.x * blockDim.x + threadIdx.x;
  int s = ei[e];
  int pos = atomicAdd(&cnt[s], 1);
  if (pos < BUCKET_CAP) bucket[s * BUCKET_CAP + pos] = e;
}

// exclusive prefix sum of clamped counts -> base[]
__global__ void prefix_k(const int* __restrict__ cnt, int* __restrict__ base) {
  __shared__ int sc[256];
  const int t = threadIdx.x;
  int c[32];
  int local = 0;
  #pragma unroll
  for (int j = 0; j < 32; ++j) {
    int v = cnt[t * 32 + j];
    v = v < BUCKET_CAP ? v : BUCKET_CAP;
    c[j] = v; local += v;
  }
  sc[t] = local;
  __syncthreads();
  #pragma unroll
  for (int off = 1; off < 256; off <<= 1) {
    int v = (t >= off) ? sc[t - off] : 0;
    __syncthreads();
    sc[t] += v;
    __syncthreads();
  }
  int run = sc[t] - local;                  // exclusive
  #pragma unroll
  for (int j = 0; j < 32; ++j) { base[t * 32 + j] = run; run += c[j]; }
}

// flatten buckets -> src-grouped order[]
__global__ void order_build_k(const int* __restrict__ cnt, const int* __restrict__ base,
                              const int* __restrict__ bucket, int* __restrict__ order) {
  int s = blockIdx.x * blockDim.x + threadIdx.x;   // 8192 threads
  int n = cnt[s]; n = n < BUCKET_CAP ? n : BUCKET_CAP;
  int b0 = base[s];
  for (int j = 0; j < n; ++j) order[b0 + j] = bucket[s * BUCKET_CAP + j];
}

// Dense GEMM: [32768 x 128] @ BmatT' -> P (cols 0..127, +b1), Q (cols 128..255).
// 512 thr / 8 waves; M-tile 256 (wave owns 32 rows); K=128; two n-passes of 128.
__global__ __launch_bounds__(512, 4) void proj_k(
    const unsigned short* __restrict__ hb,    // [32768][128] bf16
    const unsigned short* __restrict__ bt,    // BmatT [256][128] bf16 linear
    const float* __restrict__ b1,
    unsigned short* __restrict__ Pb,
    unsigned short* __restrict__ Qb) {
  __shared__ char lds[65536];                 // BmatT swizzled rows of 256 B
  const int tid  = threadIdx.x;
  const int lane = tid & 63;
  const int wid  = tid >> 6;
  const int l15  = lane & 15;
  const int lg   = lane >> 4;

  {
    const uint4* g = reinterpret_cast<const uint4*>(bt);
    #pragma unroll
    for (int it = 0; it < 8; ++it) {
      int i = it * 512 + tid;                 // uint4 idx, 4096 total
      uint4 v = g[i];
      int byte = i * 16;
      int dd = byte >> 8;
      int within = byte & 255;
      *reinterpret_cast<uint4*>(&lds[dd * 256 + (within ^ ((dd & 7) << 4))]) = v;
    }
  }
  __syncthreads();

  const int r0 = blockIdx.x * 256 + wid * 32;
  const int kg = 8 * lg;

  // A fragments: rows r0 + m*16 + l15, k-chunks ks*32+kg
  bf16x8 a[2][4];
  #pragma unroll
  for (int m = 0; m < 2; ++m) {
    unsigned rowoff = (unsigned)(r0 + m * 16 + l15) * 128u;
    #pragma unroll
    for (int ks = 0; ks < 4; ++ks) {
      u16x8 u = *reinterpret_cast<const u16x8*>(hb + rowoff + ks * 32 + kg);
      a[m][ks] = __builtin_bit_cast(bf16x8, u);
    }
  }

  #pragma unroll
  for (int pass = 0; pass < 2; ++pass) {
    f32x4 acc[2][8];
    #pragma unroll
    for (int m = 0; m < 2; ++m)
      #pragma unroll
      for (int n = 0; n < 8; ++n)
        acc[m][n] = (f32x4){0.f, 0.f, 0.f, 0.f};

    #pragma unroll
    for (int ks = 0; ks < 4; ++ks) {
      const int kb = ks * 64 + 16 * lg;
      #pragma unroll
      for (int n = 0; n < 8; ++n) {
        int dd = pass * 128 + n * 16 + l15;
        uint4 v = *reinterpret_cast<const uint4*>(&lds[dd * 256 + (kb ^ ((dd & 7) << 4))]);
        bf16x8 bfr = __builtin_bit_cast(bf16x8, v);
        acc[0][n] = __builtin_amdgcn_mfma_f32_16x16x32_bf16(a[0][ks], bfr, acc[0][n], 0, 0, 0);
        acc[1][n] = __builtin_amdgcn_mfma_f32_16x16x32_bf16(a[1][ks], bfr, acc[1][n], 0, 0, 0);
      }
    }

    unsigned short* outp = pass == 0 ? Pb : Qb;
    #pragma unroll
    for (int m = 0; m < 2; ++m)
      #pragma unroll
      for (int n = 0; n < 8; ++n) {
        int col = n * 16 + l15;
        float bias = (pass == 0) ? b1[col] : 0.f;
        #pragma unroll
        for (int i = 0; i < 4; ++i) {
          int r = r0 + m * 16 + 4 * lg + i;   // C/D: row = 4*(lane>>4)+reg
          outp[(unsigned)r * 128u + col] = f2bf(acc[m][n][i] + bias);
        }
      }
  }
}

// Per edge: score[b] = W2 . silu(P[b,src] + Q[b,dst]) + b2.
// 16-lane group g = batch; lane covers elems [l15*8, l15*8+8). 4 edges/wave-iter.
__global__ __launch_bounds__(256, 8) void edge_score_k(
    const int* __restrict__ ei,
    const int* __restrict__ order,
    const unsigned short* __restrict__ Pb,
    const unsigned short* __restrict__ Qb,
    const float* __restrict__ w2,
    const float* __restrict__ b2,
    float* __restrict__ scores) {             // [E][4]
  const int lane = threadIdx.x & 63;
  const int l15  = lane & 15;
  const int g    = lane >> 4;                 // batch
  const int wv   = blockIdx.x * 4 + (threadIdx.x >> 6);
  const int nwav = gridDim.x * 4;

  float w2v[8];
  #pragma unroll
  for (int t = 0; t < 8; ++t) w2v[t] = w2[l15 * 8 + t];
  const float b2v = b2[0];
  const unsigned gbase = (unsigned)g * N_ * 128u + (unsigned)l15 * 8u;

  for (int c = wv * 4; c < E_; c += nwav * 4) {
    u16x8 pv[4], qv[4];
    int eidx[4];
    #pragma unroll
    for (int j = 0; j < 4; ++j) {
      int e = order[c + j];
      eidx[j] = e;
      unsigned s = (unsigned)ei[e];
      unsigned d = (unsigned)ei[E_ + e];
      pv[j] = *reinterpret_cast<const u16x8*>(Pb + gbase + s * 128u);
      qv[j] = *reinterpret_cast<const u16x8*>(Qb + gbase + d * 128u);
    }
    #pragma unroll
    for (int j = 0; j < 4; ++j) {
      float acc = 0.f;
      #pragma unroll
      for (int t = 0; t < 8; ++t) {
        float z = bf2f((unsigned short)pv[j][t]) + bf2f((unsigned short)qv[j][t]);
        float sv = z / (1.f + __expf(-z));    // SiLU
        acc += sv * w2v[t];
      }
      acc += __shfl_xor(acc, 1, 64);
      acc += __shfl_xor(acc, 2, 64);
      acc += __shfl_xor(acc, 4, 64);
      acc += __shfl_xor(acc, 8, 64);
      if (l15 == 0) scores[eidx[j] * 4 + g] = acc + b2v;
    }
  }
}

// One block per src row. Dedupe (max-e wins) in LDS, mark idx8[dst]=t+1,
// then stream all 4 batches' rows with each float4 written exactly once.
__global__ __launch_bounds__(256, 8) void out_writer_k(
    const int* __restrict__ ei,
    const int* __restrict__ cnt,
    const int* __restrict__ bucket,
    const f32x4* __restrict__ scores,
    float* __restrict__ out) {
  __shared__ int dst_l[BUCKET_CAP];
  __shared__ int e_l[BUCKET_CAP];
  __shared__ float sc4[BUCKET_CAP][4];
  __shared__ unsigned int idx32[2048];        // u8 mark per dst elem (8192)
  const int t = threadIdx.x;
  const int src = blockIdx.x;
  int n = cnt[src];
  n = n < BUCKET_CAP ? n : BUCKET_CAP;
  if (t < n) {
    int e = bucket[src * BUCKET_CAP + t];
    e_l[t] = e;
    dst_l[t] = ei[E_ + e];
    f32x4 s = scores[e];
    sc4[t][0] = s[0]; sc4[t][1] = s[1]; sc4[t][2] = s[2]; sc4[t][3] = s[3];
  }
  #pragma unroll
  for (int k = 0; k < 8; ++k) idx32[t + 256 * k] = 0u;
  __syncthreads();
  if (t < n) {
    int dst = dst_l[t], e = e_l[t];
    bool win = true;
    for (int j = 0; j < n; ++j)
      win = win && !(dst_l[j] == dst && e_l[j] > e);
    if (win) reinterpret_cast<unsigned char*>(idx32)[dst] = (unsigned char)(t + 1);
  }
  __syncthreads();

  const size_t rowbase = (size_t)src * N_;
  #pragma unroll
  for (int b = 0; b < 4; ++b) {
    f32x4* po = reinterpret_cast<f32x4*>(out + (size_t)b * ((size_t)N_ * N_) + rowbase);
    #pragma unroll
    for (int k = 0; k < 8; ++k) {
      int c = t + 256 * k;                    // float4 chunk: dsts [4c, 4c+4)
      unsigned m4 = idx32[c];
      f32x4 v = (f32x4){0.f, 0.f, 0.f, 0.f};
      if (m4) {
        #pragma unroll
        for (int i = 0; i < 4; ++i) {
          unsigned mj = (m4 >> (8 * i)) & 255u;
          if (mj) v[i] = sc4[mj - 1][b];
        }
      }
      po[c] = v;                              // regular store (L2 write-combine)
    }
  }
}

extern "C" void kernel_launch(void* const* d_in, const int* in_sizes, int n_in,
                              void* d_out, int out_size, void* d_ws, size_t ws_size,
                              hipStream_t stream) {
  const float* h  = (const float*)d_in[0];
  const int*   ei = (const int*)d_in[1];     // harness stores integer inputs as int32
  const float* W1 = (const float*)d_in[2];
  const float* b1 = (const float*)d_in[3];
  const float* W2 = (const float*)d_in[4];
  const float* b2 = (const float*)d_in[5];
  float* out = (float*)d_out;
  char*  ws  = (char*)d_ws;

  unsigned short* hb     = (unsigned short*)(ws + OFF_HB);
  unsigned short* bt     = (unsigned short*)(ws + OFF_BT);
  unsigned short* Pb     = (unsigned short*)(ws + OFF_P);
  unsigned short* Qb     = (unsigned short*)(ws + OFF_Q);
  float*          scores = (float*)(ws + OFF_SCORES);
  int*            cnt    = (int*)(ws + OFF_CNT);
  int*            base   = (int*)(ws + OFF_BASE);
  int*            bucket = (int*)(ws + OFF_BUCKET);
  int*            order  = (int*)(ws + OFF_ORDER);

  (void)hipMemsetAsync(cnt, 0, (size_t)N_ * 4, stream);
  (void)hipMemsetAsync(order, 0, (size_t)E_ * 4, stream);  // safe pad if overflow

  cast_h_k<<<4096, 256, 0, stream>>>(h, hb);
  bmat_k<<<128, 256, 0, stream>>>(W1, bt);
  place_k<<<E_ / 256, 256, 0, stream>>>(ei, cnt, bucket);
  prefix_k<<<1, 256, 0, stream>>>(cnt, base);
  order_build_k<<<32, 256, 0, stream>>>(cnt, base, bucket, order);
  proj_k<<<128, 512, 0, stream>>>(hb, bt, b1, Pb, Qb);
  edge_score_k<<<2048, 256, 0, stream>>>(ei, order, Pb, Qb, W2, b2, scores);
  out_writer_k<<<N_, 256, 0, stream>>>(ei, cnt, bucket, (const f32x4*)scores, out);
}

// Round 9
// 1134.102 us; speedup vs baseline: 1.6314x; 1.0808x over previous
//
#include <hip/hip_runtime.h>
#include <hip/hip_bf16.h>
#include <stdint.h>

#define B_ 4
#define N_ 8192
#define D_ 128
#define E_ 262144

typedef __bf16 bf16x8 __attribute__((ext_vector_type(8)));
typedef unsigned short u16x8 __attribute__((ext_vector_type(8)));
typedef float f32x4 __attribute__((ext_vector_type(4)));

constexpr int BUCKET_CAP = 128;   // Poisson(32)/src; P(>=128) ~ 1e-40

// ws layout (bytes):
constexpr size_t OFF_HB     = 0;          // bf16 h [B*N][128]        8,388,608
constexpr size_t OFF_BT     = 8388608;    // bf16 BmatT [256][128]       65,536
constexpr size_t OFF_P      = 8454144;    // bf16 P [B][N][128]       8,388,608
constexpr size_t OFF_Q      = 16842752;   // bf16 Q [B][N][128]       8,388,608
constexpr size_t OFF_CNT    = 25231360;   // int cnt [N]                 32,768
constexpr size_t OFF_BUCKET = 25264128;   // int bucket [N][128]      4,194,304

__device__ __forceinline__ unsigned short f2bf(float f) {
  union { float f; unsigned u; } v; v.f = f;
  unsigned r = v.u + 0x7fffu + ((v.u >> 16) & 1u);  // RNE
  return (unsigned short)(r >> 16);
}
__device__ __forceinline__ float bf2f(unsigned short u) {
  return __uint_as_float((unsigned)u << 16);
}

__global__ void cast_h_k(const float* __restrict__ h, unsigned short* __restrict__ o) {
  int i = blockIdx.x * blockDim.x + threadIdx.x;   // 1,048,576 threads x 4 elems
  float4 v = reinterpret_cast<const float4*>(h)[i];
  ushort4 r;
  r.x = f2bf(v.x); r.y = f2bf(v.y); r.z = f2bf(v.z); r.w = f2bf(v.w);
  reinterpret_cast<ushort4*>(o)[i] = r;
}

// BmatT[d'][k], d'<128: W1[k][d'] (top half); d'>=128: W1[128+k][d'-128] (bottom)
__global__ void bmat_k(const float* __restrict__ W1, unsigned short* __restrict__ o) {
  int i = blockIdx.x * blockDim.x + threadIdx.x;   // 32768
  int dp = i >> 7, k = i & 127;
  int kk = (dp < 128) ? k : (128 + k);
  o[i] = f2bf(W1[kk * 128 + (dp & 127)]);
}

// append every edge to its src bucket (order within bucket irrelevant)
__global__ void place_k(const int* __restrict__ ei,
                        int* __restrict__ cnt, int* __restrict__ bucket) {
  int e = blockIdx.x * blockDim.x + threadIdx.x;
  int s = ei[e];
  int pos = atomicAdd(&cnt[s], 1);
  if (pos < BUCKET_CAP) bucket[s * BUCKET_CAP + pos] = e;
}

// Dense GEMM: [32768 x 128] @ BmatT' -> P (cols 0..127, +b1), Q (cols 128..255).
// 512 thr / 8 waves; M-tile 256 (wave owns 32 rows); K=128; two n-passes of 128.
__global__ __launch_bounds__(512, 4) void proj_k(
    const unsigned short* __restrict__ hb,    // [32768][128] bf16
    const unsigned short* __restrict__ bt,    // BmatT [256][128] bf16 linear
    const float* __restrict__ b1,
    unsigned short* __restrict__ Pb,
    unsigned short* __restrict__ Qb) {
  __shared__ char lds[65536];                 // BmatT swizzled rows of 256 B
  const int tid  = threadIdx.x;
  const int lane = tid & 63;
  const int wid  = tid >> 6;
  const int l15  = lane & 15;
  const int lg   = lane >> 4;

  {
    const uint4* g = reinterpret_cast<const uint4*>(bt);
    #pragma unroll
    for (int it = 0; it < 8; ++it) {
      int i = it * 512 + tid;                 // uint4 idx, 4096 total
      uint4 v = g[i];
      int byte = i * 16;
      int dd = byte >> 8;
      int within = byte & 255;
      *reinterpret_cast<uint4*>(&lds[dd * 256 + (within ^ ((dd & 7) << 4))]) = v;
    }
  }
  __syncthreads();

  const int r0 = blockIdx.x * 256 + wid * 32;
  const int kg = 8 * lg;

  // A fragments: rows r0 + m*16 + l15, k-chunks ks*32+kg
  bf16x8 a[2][4];
  #pragma unroll
  for (int m = 0; m < 2; ++m) {
    unsigned rowoff = (unsigned)(r0 + m * 16 + l15) * 128u;
    #pragma unroll
    for (int ks = 0; ks < 4; ++ks) {
      u16x8 u = *reinterpret_cast<const u16x8*>(hb + rowoff + ks * 32 + kg);
      a[m][ks] = __builtin_bit_cast(bf16x8, u);
    }
  }

  #pragma unroll
  for (int pass = 0; pass < 2; ++pass) {
    f32x4 acc[2][8];
    #pragma unroll
    for (int m = 0; m < 2; ++m)
      #pragma unroll
      for (int n = 0; n < 8; ++n)
        acc[m][n] = (f32x4){0.f, 0.f, 0.f, 0.f};

    #pragma unroll
    for (int ks = 0; ks < 4; ++ks) {
      const int kb = ks * 64 + 16 * lg;
      #pragma unroll
      for (int n = 0; n < 8; ++n) {
        int dd = pass * 128 + n * 16 + l15;
        uint4 v = *reinterpret_cast<const uint4*>(&lds[dd * 256 + (kb ^ ((dd & 7) << 4))]);
        bf16x8 bfr = __builtin_bit_cast(bf16x8, v);
        acc[0][n] = __builtin_amdgcn_mfma_f32_16x16x32_bf16(a[0][ks], bfr, acc[0][n], 0, 0, 0);
        acc[1][n] = __builtin_amdgcn_mfma_f32_16x16x32_bf16(a[1][ks], bfr, acc[1][n], 0, 0, 0);
      }
    }

    unsigned short* outp = pass == 0 ? Pb : Qb;
    #pragma unroll
    for (int m = 0; m < 2; ++m)
      #pragma unroll
      for (int n = 0; n < 8; ++n) {
        int col = n * 16 + l15;
        float bias = (pass == 0) ? b1[col] : 0.f;
        #pragma unroll
        for (int i = 0; i < 4; ++i) {
          int r = r0 + m * 16 + 4 * lg + i;   // C/D: row = 4*(lane>>4)+reg
          outp[(unsigned)r * 128u + col] = f2bf(acc[m][n][i] + bias);
        }
      }
  }
}

// One block per src row: compute scores for this src's bucket, dedupe
// (max-e wins), mark idx8[dst], stream all 4 batch rows (each float4 once).
__global__ __launch_bounds__(256, 8) void out_writer_k(
    const int* __restrict__ ei,
    const int* __restrict__ cnt,
    const int* __restrict__ bucket,
    const unsigned short* __restrict__ Pb,
    const unsigned short* __restrict__ Qb,
    const float* __restrict__ w2,
    const float* __restrict__ b2,
    float* __restrict__ out) {
  __shared__ int dst_l[BUCKET_CAP];
  __shared__ int e_l[BUCKET_CAP];
  __shared__ float sc4[BUCKET_CAP][4];
  __shared__ unsigned int idx32[2048];        // u8 mark per dst elem (8192)
  const int t = threadIdx.x;
  const int src = blockIdx.x;
  int n = cnt[src];
  n = n < BUCKET_CAP ? n : BUCKET_CAP;
  if (t < n) {
    int e = bucket[src * BUCKET_CAP + t];
    e_l[t] = e;
    dst_l[t] = ei[E_ + e];
  }
  #pragma unroll
  for (int k = 0; k < 8; ++k) idx32[t + 256 * k] = 0u;
  __syncthreads();

  // ---- score compute: 16 groups of 16 lanes; group G: batch b=G&3,
  //      edge slots j = (G>>2) + 4*iter. P row fixed per group.
  {
    const int l16 = t & 15;
    const int G   = t >> 4;
    const int b   = G & 3;
    float w2v[8];
    #pragma unroll
    for (int u = 0; u < 8; ++u) w2v[u] = w2[l16 * 8 + u];
    const float b2v = b2[0];
    const unsigned gbase = ((unsigned)b * N_) * 128u + (unsigned)l16 * 8u;
    u16x8 pv = *reinterpret_cast<const u16x8*>(Pb + gbase + (unsigned)src * 128u);
    for (int j = G >> 2; j < n; j += 4) {
      unsigned dst = (unsigned)dst_l[j];
      u16x8 qv = *reinterpret_cast<const u16x8*>(Qb + gbase + dst * 128u);
      float acc = 0.f;
      #pragma unroll
      for (int u = 0; u < 8; ++u) {
        float z = bf2f((unsigned short)pv[u]) + bf2f((unsigned short)qv[u]);
        float sv = z / (1.f + __expf(-z));    // SiLU
        acc += sv * w2v[u];
      }
      acc += __shfl_xor(acc, 1, 64);
      acc += __shfl_xor(acc, 2, 64);
      acc += __shfl_xor(acc, 4, 64);
      acc += __shfl_xor(acc, 8, 64);
      if (l16 == 0) sc4[j][b] = acc + b2v;
    }
  }
  __syncthreads();

  if (t < n) {
    int dst = dst_l[t], e = e_l[t];
    bool win = true;
    for (int j = 0; j < n; ++j)
      win = win && !(dst_l[j] == dst && e_l[j] > e);
    if (win) reinterpret_cast<unsigned char*>(idx32)[dst] = (unsigned char)(t + 1);
  }
  __syncthreads();

  const size_t rowbase = (size_t)src * N_;
  #pragma unroll
  for (int b = 0; b < 4; ++b) {
    f32x4* po = reinterpret_cast<f32x4*>(out + (size_t)b * ((size_t)N_ * N_) + rowbase);
    #pragma unroll
    for (int k = 0; k < 8; ++k) {
      int c = t + 256 * k;                    // float4 chunk: dsts [4c, 4c+4)
      unsigned m4 = idx32[c];
      f32x4 v = (f32x4){0.f, 0.f, 0.f, 0.f};
      if (m4) {
        #pragma unroll
        for (int i = 0; i < 4; ++i) {
          unsigned mj = (m4 >> (8 * i)) & 255u;
          if (mj) v[i] = sc4[mj - 1][b];
        }
      }
      po[c] = v;                              // regular store (L2 write-combine)
    }
  }
}

extern "C" void kernel_launch(void* const* d_in, const int* in_sizes, int n_in,
                              void* d_out, int out_size, void* d_ws, size_t ws_size,
                              hipStream_t stream) {
  const float* h  = (const float*)d_in[0];
  const int*   ei = (const int*)d_in[1];     // harness stores integer inputs as int32
  const float* W1 = (const float*)d_in[2];
  const float* b1 = (const float*)d_in[3];
  const float* W2 = (const float*)d_in[4];
  const float* b2 = (const float*)d_in[5];
  float* out = (float*)d_out;
  char*  ws  = (char*)d_ws;

  unsigned short* hb     = (unsigned short*)(ws + OFF_HB);
  unsigned short* bt     = (unsigned short*)(ws + OFF_BT);
  unsigned short* Pb     = (unsigned short*)(ws + OFF_P);
  unsigned short* Qb     = (unsigned short*)(ws + OFF_Q);
  int*            cnt    = (int*)(ws + OFF_CNT);
  int*            bucket = (int*)(ws + OFF_BUCKET);

  (void)hipMemsetAsync(cnt, 0, (size_t)N_ * 4, stream);

  cast_h_k<<<4096, 256, 0, stream>>>(h, hb);
  bmat_k<<<128, 256, 0, stream>>>(W1, bt);
  place_k<<<E_ / 256, 256, 0, stream>>>(ei, cnt, bucket);
  proj_k<<<128, 512, 0, stream>>>(hb, bt, b1, Pb, Qb);
  out_writer_k<<<N_, 256, 0, stream>>>(ei, cnt, bucket, Pb, Qb, W2, b2, out);
}